// Round 9
// baseline (225.349 us; speedup 1.0000x reference)
//
#include <hip/hip_runtime.h>
#include <hip/hip_cooperative_groups.h>

namespace cg = cooperative_groups;

#define B_ROWS 16384
#define K_DIM  128
#define C_CLS  32

// ws layout (bytes) — no zero-init required anywhere (all partials non-atomic)
#define O_COUNTSP 0                // 256 int  (per-block counts)
#define O_FIRSTP  1024             // 256 int  (per-block first-row)
#define O_RANK    2048             // 32 int
#define O_LD2     2304             // 32 float
#define O_MU      2560             // 32*128*4 = 16 KiB (ends 18944)
#define O_COLSUMP 20480            // 256*128*4 = 128 KiB
#define O_S       151552           // 2 MiB
#define O_PART    2248704          // NSPLIT*32 slabs * 64 KiB
// INV for class c aliases class c's OWN partial slab (part + c*NSPLIT*16384):
// block c reads its slabs (finalize) then writes INV -> block-private, race-free.

// ---------------------------------------------------------------------------
// Single cooperative mega-kernel, 256 blocks x 512 threads.
// PHASE = -1: all phases with cg grid sync (cooperative launch).
// PHASE = 0/1/2: single phase (fallback path; kernel boundary = sync).
//
// Phase A (blocks < 32*NSPLIT): ballot-compaction scatter -> 64KB Gram
//   partial + colsum/count/first partials, all block-private (r5/r8-proven).
// Phase B (blocks < 32): fused finalize + rolled parked-diag sweep inversion
//   + log2-det — EXACTLY the r4-verified 512-thread structure (55.2 us,
//   absmax 0): rows rq = 16q+h (h=t>>5), cols 4*(t&31); one 512B LDS pivot
//   broadcast + 1 barrier per step, double-buffered vbuf; exported row P
//   carries d-1 at slot P (raw d at slot 128) so the generic rank-1 update
//   is exact for row P and col P; diag[P][P] ends up off by exactly +2,
//   fixed in the final write INV = -A + 2*[diag].
// Phase C (all blocks): 4 KL pairs each (fused tr+quad) + block 0 adds
//   -sum(mu^2); accumulates into d_out (zeroed in phase A).
// ---------------------------------------------------------------------------
template<int NSPLIT, int PHASE>
__global__ __launch_bounds__(512) void k_mega(const float* __restrict__ feat,
    const int* __restrict__ label, float* __restrict__ out, char* __restrict__ ws) {
  int*   counts_p = (int*)(ws + O_COUNTSP);
  int*   first_p  = (int*)(ws + O_FIRSTP);
  int*   rank_g   = (int*)(ws + O_RANK);
  float* ld2      = (float*)(ws + O_LD2);
  float* mu       = (float*)(ws + O_MU);
  float* colsum_p = (float*)(ws + O_COLSUMP);
  float* S        = (float*)(ws + O_S);
  float* part     = (float*)(ws + O_PART);

  constexpr int CH = B_ROWS / NSPLIT;
  const int bid = blockIdx.x, t = threadIdx.x;

  __shared__ int   lls[CH];
  __shared__ int   lcnt, lmin;
  __shared__ __align__(16) float ls[32 * 128];
  __shared__ float lcs[512];
  __shared__ __align__(16) float ml[128];
  __shared__ __align__(16) float vbuf[2][132];   // slot [128] carries d
  __shared__ int   lfirst[C_CLS];
  __shared__ __align__(16) float dl[128];
  __shared__ float wsum[8];

  // ============================ PHASE A: scatter ===========================
  if constexpr (PHASE == -1 || PHASE == 0) {
    if (bid == 0 && t == 0) out[0] = 0.f;
    if (bid < C_CLS * NSPLIT) {
      const int c = bid / NSPLIT, s = bid % NSPLIT;
      if (t == 0) { lcnt = 0; lmin = 0x7fffffff; }
      __syncthreads();
      int myMin = 0x7fffffff;
      const int lane = t & 63;
      for (int r0 = 0; r0 < CH; r0 += 512) {
        const int i = s * CH + r0 + t;
        const bool match = (label[i] == c);
        unsigned long long mask = __ballot(match);
        int prefix = __popcll(mask & ((1ull << lane) - 1ull));
        int wcnt = __popcll(mask);
        int base = 0;
        if (lane == 0 && wcnt) base = atomicAdd(&lcnt, wcnt);
        base = __shfl(base, 0);
        if (match) { lls[base + prefix] = i; myMin = min(myMin, i); }
      }
      #pragma unroll
      for (int off = 32; off > 0; off >>= 1) myMin = min(myMin, __shfl_xor(myMin, off));
      if (lane == 0) atomicMin(&lmin, myMin);   // LDS atomic, 8/block
      __syncthreads();
      const int n = lcnt;
      if (t == 0) { counts_p[bid] = n; first_p[bid] = lmin; }
      // Gram: thread owns output rows 8*tr..8*tr+7 x cols 4*tc..4*tc+3
      const int tr = t >> 5, tc = t & 31;
      float acc[8][4];
      #pragma unroll
      for (int i = 0; i < 8; ++i)
        #pragma unroll
        for (int j = 0; j < 4; ++j) acc[i][j] = 0.f;
      float cs = 0.f;
      const int col = t & 127, quar = t >> 7;
      for (int b2 = 0; b2 < n; b2 += 32) {
        const int nb = min(32, n - b2);
        __syncthreads();           // protect ls against previous-iter readers
        #pragma unroll
        for (int w = 0; w < 2; ++w) {
          int f4 = w * 512 + t;    // 0..1023 over 32 rows x 32 float4
          int r = f4 >> 5, c4 = f4 & 31;
          float4 v = make_float4(0.f, 0.f, 0.f, 0.f);
          if (r < nb) v = ((const float4*)(feat + (long)lls[b2 + r] * K_DIM))[c4];
          ((float4*)ls)[f4] = v;   // zero-padded tail rows contribute nothing
        }
        __syncthreads();
        #pragma unroll
        for (int r0 = 0; r0 < 8; ++r0) cs += ls[(quar * 8 + r0) * 128 + col];
        for (int r = 0; r < nb; ++r) {
          const float4* lr = (const float4*)(ls + r * 128);
          float4 A0 = lr[tr * 2], A1 = lr[tr * 2 + 1], B0 = lr[tc];
          float av[8] = {A0.x, A0.y, A0.z, A0.w, A1.x, A1.y, A1.z, A1.w};
          float bv[4] = {B0.x, B0.y, B0.z, B0.w};
          #pragma unroll
          for (int i = 0; i < 8; ++i)
            #pragma unroll
            for (int j = 0; j < 4; ++j) acc[i][j] += av[i] * bv[j];
        }
      }
      float* Pc = part + (long)bid * 16384;
      #pragma unroll
      for (int i = 0; i < 8; ++i)
        ((float4*)(Pc + (tr * 8 + i) * 128))[tc] =
            make_float4(acc[i][0], acc[i][1], acc[i][2], acc[i][3]);
      lcs[t] = cs;
      __syncthreads();
      if (t < 128)
        colsum_p[bid * 128 + t] = (lcs[t] + lcs[t + 128]) + (lcs[t + 256] + lcs[t + 384]);
    }
  }
  if constexpr (PHASE == -1) cg::this_grid().sync();

  // ============================ PHASE B: sweep =============================
  if constexpr (PHASE == -1 || PHASE == 1) {
    if (bid < C_CLS) {
      const int c = bid;
      int n = 0;
      #pragma unroll
      for (int k = 0; k < NSPLIT; ++k) n += counts_p[c * NSPLIT + k];
      const float rn = 1.0f / (float)n;
      if (t < 128) {
        float m = 0.f;
        #pragma unroll
        for (int k = 0; k < NSPLIT; ++k) m += colsum_p[(c * NSPLIT + k) * 128 + t];
        m *= rn;
        ml[t] = m;
        mu[c * 128 + t] = m;
      }
      if (t < C_CLS) {
        int f = 0x7fffffff;
        #pragma unroll
        for (int k = 0; k < NSPLIT; ++k) f = min(f, first_p[t * NSPLIT + k]);
        lfirst[t] = f;
      }
      __syncthreads();
      if (t == 0) {
        const int f = lfirst[c];
        int r = 0;
        for (int c2 = 0; c2 < C_CLS; ++c2)
          r += (lfirst[c2] < f) || (lfirst[c2] == f && c2 < c);
        rank_g[c] = r;
      }
      // ---- inline finalize: A = (sum partials)*rn - mu mu^T + I ; write S ----
      const int h = t >> 5, c4i = t & 31;     // rows rq = 16q+h, f4col c4i
      float4 A[8];
      float4* S4 = (float4*)(S + c * 16384);
      #pragma unroll
      for (int q = 0; q < 8; ++q) {
        const int f4 = q * 512 + t;
        float4 v = make_float4(0.f, 0.f, 0.f, 0.f);
        #pragma unroll
        for (int k = 0; k < NSPLIT; ++k) {
          const float4 p = ((const float4*)(part + (long)(c * NSPLIT + k) * 16384))[f4];
          v.x += p.x; v.y += p.y; v.z += p.z; v.w += p.w;
        }
        const int row = q * 16 + h;
        const float mr = ml[row];
        const float4 mc = ((const float4*)ml)[c4i];
        const int b = 4 * c4i;
        v.x = v.x * rn - mr * mc.x + ((row == b + 0) ? 1.f : 0.f);
        v.y = v.y * rn - mr * mc.y + ((row == b + 1) ? 1.f : 0.f);
        v.z = v.z * rn - mr * mc.z + ((row == b + 2) ? 1.f : 0.f);
        v.w = v.w * rn - mr * mc.w + ((row == b + 3) ? 1.f : 0.f);
        A[q] = v;
        S4[f4] = v;
      }
      // ---- rolled parked-diag sweep (r4-verified structure) ----
      float lda = 0.f;
      for (int P = 0; P < 128; ++P) {
        float* vb = vbuf[P & 1];
        if (h == (P & 15)) {                  // export row P with in-LDS fixup
          const int qexp = P >> 4;
          float4 ex = A[0];
          #pragma unroll
          for (int q = 1; q < 8; ++q) if (q == qexp) ex = A[q];  // static select
          if (c4i == (P >> 2)) {              // this float4 holds col P (diag d)
            const int e = P & 3;
            float dv = (e == 0) ? ex.x : (e == 1) ? ex.y : (e == 2) ? ex.z : ex.w;
            vb[128] = dv;                     // broadcast raw d
            if (e == 0) ex.x -= 1.f; else if (e == 1) ex.y -= 1.f;
            else if (e == 2) ex.z -= 1.f; else ex.w -= 1.f;      // slot P = d-1
          }
          ((float4*)vb)[c4i] = ex;
        }
        __syncthreads();
        const float d = vb[128];
        const float dinv = 1.0f / d;
        lda += __log2f(d);
        const float4 vc = ((const float4*)vb)[c4i];
        const float4 wc = make_float4(vc.x * dinv, vc.y * dinv, vc.z * dinv, vc.w * dinv);
        #pragma unroll
        for (int q = 0; q < 8; ++q) {
          const float vr = vb[q * 16 + h];    // row-P lane reads d-1 automatically
          A[q].x -= vr * wc.x;
          A[q].y -= vr * wc.y;
          A[q].z -= vr * wc.z;
          A[q].w -= vr * wc.w;
        }
        // dbuf parity: writes to buf[(P+1)&1] vs step-(P-1) readers separated
        // by step P's barrier.
      }
      // ---- INV = -A + 2*[diag], into class c's OWN first partial slab ----
      float4* O4 = (float4*)(part + (long)c * NSPLIT * 16384);
      const int e = h & 3;                    // rq & 3 == h & 3 (16q = 0 mod 4)
      #pragma unroll
      for (int q = 0; q < 8; ++q) {
        const int rq = q * 16 + h;
        const float pf = (c4i == (rq >> 2)) ? 2.f : 0.f;
        float4 o;
        o.x = ((e == 0) ? pf : 0.f) - A[q].x;
        o.y = ((e == 1) ? pf : 0.f) - A[q].y;
        o.z = ((e == 2) ? pf : 0.f) - A[q].z;
        o.w = ((e == 3) ? pf : 0.f) - A[q].w;
        O4[q * 512 + t] = o;
      }
      if (t == 0) ld2[c] = lda;       // v_log_f32 is log2 = slogdet/ln2
    }
  }
  if constexpr (PHASE == -1) cg::this_grid().sync();

  // ============================ PHASE C: pairs =============================
  if constexpr (PHASE == -1 || PHASE == 2) {
    if (bid == 0) {                   // fused -sum(mu^2)
      float s2 = 0.f;
      #pragma unroll
      for (int q = 0; q < 8; ++q) { float m = mu[q * 512 + t]; s2 += m * m; }
      #pragma unroll
      for (int off = 32; off > 0; off >>= 1) s2 += __shfl_xor(s2, off);
      if ((t & 63) == 0) wsum[t >> 6] = s2;
      __syncthreads();
      if (t == 0) {
        float tot = 0.f;
        #pragma unroll
        for (int w = 0; w < 8; ++w) tot += wsum[w];
        atomicAdd(out, -tot);
      }
    }
    const long invStride = (long)NSPLIT * 16384;
    for (int p = bid * 4; p < bid * 4 + 4; ++p) {
      const int j = p & 31, i = p >> 5;
      if (rank_g[i] > C_CLS - 2 || rank_g[j] < 1) continue;  // block-uniform
      __syncthreads();                // prior iteration's wsum/dl fully read
      if (t < 128) dl[t] = mu[i * 128 + t] - mu[j * 128 + t];
      __syncthreads();
      const float4* Si4 = (const float4*)(S + i * 16384);
      const float4* Ij4 = (const float4*)(part + (long)j * invStride);
      float s = 0.f;
      #pragma unroll
      for (int q = 0; q < 8; ++q) {
        int f4 = q * 512 + t;
        int a = f4 >> 5, b4 = f4 & 31;
        float da = dl[a];
        float4 db = ((const float4*)dl)[b4];
        float4 si = Si4[f4], ij = Ij4[f4];
        s += ij.x * (si.x + da * db.x);
        s += ij.y * (si.y + da * db.y);
        s += ij.z * (si.z + da * db.z);
        s += ij.w * (si.w + da * db.w);
      }
      #pragma unroll
      for (int off = 32; off > 0; off >>= 1) s += __shfl_xor(s, off);
      if ((t & 63) == 0) wsum[t >> 6] = s;
      __syncthreads();
      if (t == 0) {
        float tot = 0.f;
        #pragma unroll
        for (int w = 0; w < 8; ++w) tot += wsum[w];
        atomicAdd(out, 0.5f * ((ld2[j] - ld2[i]) - 128.0f + tot));
      }
    }
  }
}

extern "C" void kernel_launch(void* const* d_in, const int* in_sizes, int n_in,
                              void* d_out, int out_size, void* d_ws, size_t ws_size,
                              hipStream_t stream) {
  const float* feat  = (const float*)d_in[0];
  const int*   label = (const int*)d_in[1];
  // d_in[2] (pan) is unused by the reference module.
  float* out = (float*)d_out;
  char*  ws  = (char*)d_ws;

  const size_t need8 = (size_t)O_PART + (size_t)C_CLS * 8 * 65536;
  void* args[] = {(void*)&feat, (void*)&label, (void*)&out, (void*)&ws};

  if (ws_size >= need8) {
    hipError_t err = hipLaunchCooperativeKernel(k_mega<8, -1>, dim3(256), dim3(512),
                                                args, 0u, stream);
    if (err != hipSuccess) {          // fallback: 3 phase launches (sync = boundary)
      (void)hipGetLastError();
      k_mega<8, 0><<<256, 512, 0, stream>>>(feat, label, out, ws);
      k_mega<8, 1><<<256, 512, 0, stream>>>(feat, label, out, ws);
      k_mega<8, 2><<<256, 512, 0, stream>>>(feat, label, out, ws);
    }
  } else {
    hipError_t err = hipLaunchCooperativeKernel(k_mega<4, -1>, dim3(256), dim3(512),
                                                args, 0u, stream);
    if (err != hipSuccess) {
      (void)hipGetLastError();
      k_mega<4, 0><<<256, 512, 0, stream>>>(feat, label, out, ws);
      k_mega<4, 1><<<256, 512, 0, stream>>>(feat, label, out, ws);
      k_mega<4, 2><<<256, 512, 0, stream>>>(feat, label, out, ws);
    }
  }
}

// Round 11
// 212.565 us; speedup vs baseline: 1.0601x; 1.0601x over previous
//
#include <hip/hip_runtime.h>

#define B_ROWS 16384
#define K_DIM  128
#define C_CLS  32

// ws layout (bytes) — no zero-init required anywhere (all partials non-atomic)
#define O_COUNTSP 0                // 256 int  (per-block counts)
#define O_FIRSTP  1024             // 256 int  (per-block first-row)
#define O_RANK    2048             // 32 int
#define O_LD2     2304             // 32 float
#define O_MU      2560             // 32*128*4 = 16 KiB
#define O_COLSUMP 20480            // 256*128*4 = 128 KiB
#define O_S       151552           // 2 MiB
#define O_PART    2248704          // NSPLIT*32 slabs * 64 KiB
// INV for class c goes to class c's OWN first partial slab
// (part + c*NSPLIT*16384): the sweep block that reads class c's partials is
// the only writer of that region -> block-private, race-free.

// ---------------------------------------------------------------------------
// K2: per-class partial second moments, fully atomic-free (r8-proven).
// ---------------------------------------------------------------------------
template<int NSPLIT>
__global__ __launch_bounds__(256) void k_scatter(const float* __restrict__ feat,
    const int* __restrict__ label, int* __restrict__ counts_p,
    int* __restrict__ first_p, float* __restrict__ part,
    float* __restrict__ colsum_p) {
  constexpr int CH = B_ROWS / NSPLIT;
  const int bid = blockIdx.x;
  const int c = bid / NSPLIT, s = bid % NSPLIT;
  __shared__ int lls[CH];
  __shared__ int lcnt, lmin;
  __shared__ __align__(16) float ls[32 * 128];
  __shared__ float lcs[256];
  const int t = threadIdx.x;
  if (t == 0) { lcnt = 0; lmin = 0x7fffffff; }
  __syncthreads();
  int myMin = 0x7fffffff;
  const int lane = t & 63;
  for (int r0 = 0; r0 < CH; r0 += 256) {
    const int i = s * CH + r0 + t;
    const bool match = (label[i] == c);
    unsigned long long mask = __ballot(match);
    int prefix = __popcll(mask & ((1ull << lane) - 1ull));
    int wcnt = __popcll(mask);
    int base = 0;
    if (lane == 0 && wcnt) base = atomicAdd(&lcnt, wcnt);
    base = __shfl(base, 0);
    if (match) { lls[base + prefix] = i; myMin = min(myMin, i); }
  }
  #pragma unroll
  for (int off = 32; off > 0; off >>= 1) myMin = min(myMin, __shfl_xor(myMin, off));
  if (lane == 0) atomicMin(&lmin, myMin);   // LDS atomic, 4/block
  __syncthreads();
  const int n = lcnt;
  if (t == 0) { counts_p[bid] = n; first_p[bid] = lmin; }

  const int tr = t >> 4, tc = t & 15;
  float acc[8][8];
  #pragma unroll
  for (int i = 0; i < 8; ++i)
    #pragma unroll
    for (int j = 0; j < 8; ++j) acc[i][j] = 0.f;
  float cs = 0.f;
  const int col = t & 127, half = t >> 7;
  for (int base2 = 0; base2 < n; base2 += 32) {
    const int nb = min(32, n - base2);
    __syncthreads();             // protect ls against previous-iter readers
    #pragma unroll
    for (int w = 0; w < 4; ++w) {
      int f4 = w * 256 + t;      // 0..1023 over 32 rows x 32 float4
      int r = f4 >> 5, c4 = f4 & 31;
      float4 v = make_float4(0.f, 0.f, 0.f, 0.f);
      if (r < nb) v = ((const float4*)(feat + (long)lls[base2 + r] * K_DIM))[c4];
      ((float4*)ls)[f4] = v;     // zero-padded tail rows contribute nothing
    }
    __syncthreads();
    #pragma unroll
    for (int r0 = 0; r0 < 16; ++r0) cs += ls[(half * 16 + r0) * 128 + col];
    for (int r = 0; r < nb; ++r) {
      const float4* lr = (const float4*)(ls + r * 128);
      float4 A0 = lr[tr * 2], A1 = lr[tr * 2 + 1];
      float4 B0 = lr[tc * 2], B1 = lr[tc * 2 + 1];
      float av[8] = {A0.x, A0.y, A0.z, A0.w, A1.x, A1.y, A1.z, A1.w};
      float bv[8] = {B0.x, B0.y, B0.z, B0.w, B1.x, B1.y, B1.z, B1.w};
      #pragma unroll
      for (int i = 0; i < 8; ++i)
        #pragma unroll
        for (int j = 0; j < 8; ++j) acc[i][j] += av[i] * bv[j];
    }
  }
  float* Pc = part + (long)bid * 16384;
  #pragma unroll
  for (int i = 0; i < 8; ++i) {
    float4* prow = (float4*)(Pc + (tr * 8 + i) * 128);
    prow[tc * 2]     = make_float4(acc[i][0], acc[i][1], acc[i][2], acc[i][3]);
    prow[tc * 2 + 1] = make_float4(acc[i][4], acc[i][5], acc[i][6], acc[i][7]);
  }
  lcs[t] = cs;
  __syncthreads();
  if (t < 128) colsum_p[bid * 128 + t] = lcs[t] + lcs[t + 128];
}

// ---------------------------------------------------------------------------
// K4: fused finalize + rolled parked-diag sweep, TWO CLASSES PER BLOCK.
// r10: r5 (8 waves) and r7 (16 waves) both measured ~1030 cy/step -> the
// step is a serial latency chain (barrier -> ds_read d ~120cy -> rcp -> wc
// -> update), not issue-bound. Interleaving two independent sweeps on the
// SAME barrier amortizes that chain: 2x work/step at ~1.1-1.3x step cost.
// Per class: r7/r8-verified layout (1024 thr, rows rq=32q+h, cols 4*(t&31),
// A[4] float4); parked-diag export (slot P = d-1, raw d at slot 128) makes
// the generic rank-1 update exact for row/col P; diag off by exactly +2,
// fixed at the final write INV = -A + 2*[diag].
// ---------------------------------------------------------------------------
template<int NSPLIT>
__global__ __launch_bounds__(1024) void k_sweepf(float* __restrict__ part,
    const float* __restrict__ colsum_p, const int* __restrict__ counts_p,
    const int* __restrict__ first_p, float* __restrict__ S,
    float* __restrict__ mu, int* __restrict__ rank_g, float* __restrict__ ld2,
    float* __restrict__ out) {
  const int b = blockIdx.x, t = threadIdx.x;
  const int c0 = 2 * b, c1 = 2 * b + 1;
  __shared__ __align__(16) float ml[2][128];
  __shared__ __align__(16) float vbuf[2][2][132];   // [cls][parity][slot]
  __shared__ int lfirst[C_CLS];
  if (b == 0 && t == 0) out[0] = 0.f;               // k_pairs accumulates later
  int n0 = 0, n1 = 0;
  #pragma unroll
  for (int k = 0; k < NSPLIT; ++k) {
    n0 += counts_p[c0 * NSPLIT + k];
    n1 += counts_p[c1 * NSPLIT + k];
  }
  const float rn0 = 1.0f / (float)n0, rn1 = 1.0f / (float)n1;
  if (t < 128) {
    float m0 = 0.f, m1 = 0.f;
    #pragma unroll
    for (int k = 0; k < NSPLIT; ++k) {
      m0 += colsum_p[(c0 * NSPLIT + k) * 128 + t];
      m1 += colsum_p[(c1 * NSPLIT + k) * 128 + t];
    }
    m0 *= rn0; m1 *= rn1;
    ml[0][t] = m0; ml[1][t] = m1;
    mu[c0 * 128 + t] = m0; mu[c1 * 128 + t] = m1;
  }
  if (t < C_CLS) {
    int f = 0x7fffffff;
    #pragma unroll
    for (int k = 0; k < NSPLIT; ++k) f = min(f, first_p[t * NSPLIT + k]);
    lfirst[t] = f;
  }
  __syncthreads();
  if (t < 2) {
    const int c = (t == 0) ? c0 : c1;
    const int f = lfirst[c];
    int r = 0;
    for (int c2 = 0; c2 < C_CLS; ++c2)
      r += (lfirst[c2] < f) || (lfirst[c2] == f && c2 < c);
    rank_g[c] = r;
  }
  // ---- inline finalize both classes; write S ----
  const int h = t >> 5, c4i = t & 31;               // rows rq = 32q+h
  float4 A0[4], A1[4];
  float4* S40 = (float4*)(S + c0 * 16384);
  float4* S41 = (float4*)(S + c1 * 16384);
  #pragma unroll
  for (int q = 0; q < 4; ++q) {
    const int f4 = q * 1024 + t;
    float4 v0 = make_float4(0.f, 0.f, 0.f, 0.f);
    float4 v1 = make_float4(0.f, 0.f, 0.f, 0.f);
    #pragma unroll
    for (int k = 0; k < NSPLIT; ++k) {
      const float4 p0 = ((const float4*)(part + (long)(c0 * NSPLIT + k) * 16384))[f4];
      const float4 p1 = ((const float4*)(part + (long)(c1 * NSPLIT + k) * 16384))[f4];
      v0.x += p0.x; v0.y += p0.y; v0.z += p0.z; v0.w += p0.w;
      v1.x += p1.x; v1.y += p1.y; v1.z += p1.z; v1.w += p1.w;
    }
    const int row = q * 32 + h;
    const float mr0 = ml[0][row], mr1 = ml[1][row];
    const float4 mc0 = ((const float4*)ml[0])[c4i];
    const float4 mc1 = ((const float4*)ml[1])[c4i];
    const int bb = 4 * c4i;
    const float i0 = (row == bb + 0) ? 1.f : 0.f;
    const float i1 = (row == bb + 1) ? 1.f : 0.f;
    const float i2 = (row == bb + 2) ? 1.f : 0.f;
    const float i3 = (row == bb + 3) ? 1.f : 0.f;
    v0.x = v0.x * rn0 - mr0 * mc0.x + i0;  v1.x = v1.x * rn1 - mr1 * mc1.x + i0;
    v0.y = v0.y * rn0 - mr0 * mc0.y + i1;  v1.y = v1.y * rn1 - mr1 * mc1.y + i1;
    v0.z = v0.z * rn0 - mr0 * mc0.z + i2;  v1.z = v1.z * rn1 - mr1 * mc1.z + i2;
    v0.w = v0.w * rn0 - mr0 * mc0.w + i3;  v1.w = v1.w * rn1 - mr1 * mc1.w + i3;
    A0[q] = v0; A1[q] = v1;
    S40[f4] = v0; S41[f4] = v1;
  }
  __syncthreads();                 // ml reads done before vbuf aliasing concerns
  // ---- interleaved rolled sweeps, one barrier per step ----
  float lda0 = 0.f, lda1 = 0.f;
  for (int P = 0; P < 128; ++P) {
    float* vb0 = vbuf[0][P & 1];
    float* vb1 = vbuf[1][P & 1];
    if (h == (P & 31)) {           // export row P of both classes, with fixup
      const int qexp = P >> 5;
      float4 e0 = A0[0], e1 = A1[0];
      #pragma unroll
      for (int q = 1; q < 4; ++q)
        if (q == qexp) { e0 = A0[q]; e1 = A1[q]; }   // static-index select
      if (c4i == (P >> 2)) {       // this float4 holds col P (diag d)
        const int e = P & 3;
        const float d0 = (e == 0) ? e0.x : (e == 1) ? e0.y : (e == 2) ? e0.z : e0.w;
        const float d1 = (e == 0) ? e1.x : (e == 1) ? e1.y : (e == 2) ? e1.z : e1.w;
        vb0[128] = d0; vb1[128] = d1;
        if (e == 0) { e0.x -= 1.f; e1.x -= 1.f; }
        else if (e == 1) { e0.y -= 1.f; e1.y -= 1.f; }
        else if (e == 2) { e0.z -= 1.f; e1.z -= 1.f; }
        else { e0.w -= 1.f; e1.w -= 1.f; }           // slot P = d-1
      }
      ((float4*)vb0)[c4i] = e0;
      ((float4*)vb1)[c4i] = e1;
    }
    __syncthreads();
    const float d0 = vb0[128],      d1 = vb1[128];
    const float di0 = 1.0f / d0,    di1 = 1.0f / d1;
    lda0 += __log2f(d0);            lda1 += __log2f(d1);
    const float4 vc0 = ((const float4*)vb0)[c4i];
    const float4 vc1 = ((const float4*)vb1)[c4i];
    const float4 wc0 = make_float4(vc0.x * di0, vc0.y * di0, vc0.z * di0, vc0.w * di0);
    const float4 wc1 = make_float4(vc1.x * di1, vc1.y * di1, vc1.z * di1, vc1.w * di1);
    #pragma unroll
    for (int q = 0; q < 4; ++q) {
      const float vr0 = vb0[q * 32 + h];   // row-P lane reads d-1 automatically
      const float vr1 = vb1[q * 32 + h];
      A0[q].x -= vr0 * wc0.x;  A1[q].x -= vr1 * wc1.x;
      A0[q].y -= vr0 * wc0.y;  A1[q].y -= vr1 * wc1.y;
      A0[q].z -= vr0 * wc0.z;  A1[q].z -= vr1 * wc1.z;
      A0[q].w -= vr0 * wc0.w;  A1[q].w -= vr1 * wc1.w;
    }
    // dbuf parity: iter P's export writes buf[P&1], last read at iter P-2,
    // separated by iter P-1's barrier (same argument as r7, per class).
  }
  // ---- INV = -A + 2*[diag] into each class's own first partial slab ----
  float4* O40 = (float4*)(part + (long)c0 * NSPLIT * 16384);
  float4* O41 = (float4*)(part + (long)c1 * NSPLIT * 16384);
  const int e = h & 3;             // rq & 3 == h & 3 (32q = 0 mod 4)
  #pragma unroll
  for (int q = 0; q < 4; ++q) {
    const int rq = q * 32 + h;
    const float pf = (c4i == (rq >> 2)) ? 2.f : 0.f;
    float4 o0, o1;
    o0.x = ((e == 0) ? pf : 0.f) - A0[q].x;  o1.x = ((e == 0) ? pf : 0.f) - A1[q].x;
    o0.y = ((e == 1) ? pf : 0.f) - A0[q].y;  o1.y = ((e == 1) ? pf : 0.f) - A1[q].y;
    o0.z = ((e == 2) ? pf : 0.f) - A0[q].z;  o1.z = ((e == 2) ? pf : 0.f) - A1[q].z;
    o0.w = ((e == 3) ? pf : 0.f) - A0[q].w;  o1.w = ((e == 3) ? pf : 0.f) - A1[q].w;
    O40[q * 1024 + t] = o0;
    O41[q * 1024 + t] = o1;
  }
  if (t == 0) { ld2[c0] = lda0; ld2[c1] = lda1; }   // log2 = slogdet/ln2
}

// ---------------------------------------------------------------------------
// K5: pairwise KL, ONE BLOCK PER ROW i (r10: was 1024 blocks x 1 same-address
// device atomic each — serialized RMWs, the suspected ~40-60us hidden cost).
// S_i and mu_i in registers; all mu staged once in LDS; barrier-free j-loop
// accumulates sum_j tr+quad per-thread; ld2/-128 terms aggregated
// analytically; ONE reduction + ONE atomic per block (+ mu^2 on block 0).
// ---------------------------------------------------------------------------
__global__ __launch_bounds__(256) void k_pairs(const float* __restrict__ S,
    const float* __restrict__ part, const long invStride,
    const float* __restrict__ mu, const float* __restrict__ ld2,
    const int* __restrict__ rank_g, float* __restrict__ out) {
  const int i = blockIdx.x, t = threadIdx.x;
  __shared__ __align__(16) float lmu[C_CLS][128];   // 16 KB
  __shared__ float lld[C_CLS];
  __shared__ int   lrank[C_CLS];
  __shared__ float wsum[4];
  #pragma unroll
  for (int q = 0; q < 4; ++q) {
    const int f4 = q * 256 + t;                     // 1024 float4 total
    ((float4*)lmu)[f4] = ((const float4*)mu)[f4];
  }
  if (t < C_CLS) { lld[t] = ld2[t]; lrank[t] = rank_g[t]; }
  __syncthreads();
  const bool activeI = (lrank[i] <= C_CLS - 2);     // block-uniform
  float s = 0.f;
  if (activeI) {
    const int h5 = t >> 5, b4 = t & 31;
    float4 Si[16];
    float  mur[16];
    const float4* Si4 = (const float4*)(S + i * 16384);
    #pragma unroll
    for (int q = 0; q < 16; ++q) Si[q] = Si4[q * 256 + t];
    #pragma unroll
    for (int q = 0; q < 16; ++q) mur[q] = lmu[i][q * 8 + h5];
    const float4 cmu_i = ((const float4*)lmu[i])[b4];
    for (int j = 0; j < C_CLS; ++j) {
      if (lrank[j] < 1) continue;                   // block-uniform
      const float4* Ij4 = (const float4*)(part + (long)j * invStride);
      const float4 cmu_j = ((const float4*)lmu[j])[b4];
      const float4 dc = make_float4(cmu_i.x - cmu_j.x, cmu_i.y - cmu_j.y,
                                    cmu_i.z - cmu_j.z, cmu_i.w - cmu_j.w);
      #pragma unroll
      for (int q = 0; q < 16; ++q) {
        const float dr = mur[q] - lmu[j][q * 8 + h5];
        const float4 ij = Ij4[q * 256 + t];
        const float4 si = Si[q];
        s += ij.x * (si.x + dr * dc.x);
        s += ij.y * (si.y + dr * dc.y);
        s += ij.z * (si.z + dr * dc.z);
        s += ij.w * (si.w + dr * dc.w);
      }
    }
  }
  #pragma unroll
  for (int off = 32; off > 0; off >>= 1) s += __shfl_xor(s, off);
  if ((t & 63) == 0) wsum[t >> 6] = s;
  __syncthreads();
  if (t == 0 && activeI) {
    const float stot = wsum[0] + wsum[1] + wsum[2] + wsum[3];
    float sld = 0.f; int nJ = 0;
    for (int j = 0; j < C_CLS; ++j)
      if (lrank[j] >= 1) { sld += lld[j]; ++nJ; }
    atomicAdd(out, 0.5f * (stot + sld - (float)nJ * (lld[i] + 128.0f)));
  }
  if (i == 0) {                                     // fused -sum(mu^2), once
    __syncthreads();                                // wsum reuse
    float s2 = 0.f;
    #pragma unroll
    for (int q = 0; q < 16; ++q) {
      const float m = ((const float*)lmu)[q * 256 + t];
      s2 += m * m;
    }
    #pragma unroll
    for (int off = 32; off > 0; off >>= 1) s2 += __shfl_xor(s2, off);
    if ((t & 63) == 0) wsum[t >> 6] = s2;
    __syncthreads();
    if (t == 0) atomicAdd(out, -(wsum[0] + wsum[1] + wsum[2] + wsum[3]));
  }
}

extern "C" void kernel_launch(void* const* d_in, const int* in_sizes, int n_in,
                              void* d_out, int out_size, void* d_ws, size_t ws_size,
                              hipStream_t stream) {
  const float* feat  = (const float*)d_in[0];
  const int*   label = (const int*)d_in[1];
  // d_in[2] (pan) is unused by the reference module.
  float* out = (float*)d_out;
  char*  ws  = (char*)d_ws;

  int*   counts_p = (int*)(ws + O_COUNTSP);
  int*   first_p  = (int*)(ws + O_FIRSTP);
  int*   rank_g   = (int*)(ws + O_RANK);
  float* ld2      = (float*)(ws + O_LD2);
  float* mu       = (float*)(ws + O_MU);
  float* colsum_p = (float*)(ws + O_COLSUMP);
  float* S        = (float*)(ws + O_S);
  float* part     = (float*)(ws + O_PART);

  const size_t need8 = (size_t)O_PART + (size_t)C_CLS * 8 * 65536;

  if (ws_size >= need8) {
    k_scatter<8><<<C_CLS * 8,  256,  0, stream>>>(feat, label, counts_p, first_p, part, colsum_p);
    k_sweepf<8> <<<C_CLS / 2,  1024, 0, stream>>>(part, colsum_p, counts_p, first_p, S, mu, rank_g, ld2, out);
    k_pairs     <<<C_CLS,      256,  0, stream>>>(S, part, (long)8 * 16384, mu, ld2, rank_g, out);
  } else {
    k_scatter<4><<<C_CLS * 4,  256,  0, stream>>>(feat, label, counts_p, first_p, part, colsum_p);
    k_sweepf<4> <<<C_CLS / 2,  1024, 0, stream>>>(part, colsum_p, counts_p, first_p, S, mu, rank_g, ld2, out);
    k_pairs     <<<C_CLS,      256,  0, stream>>>(S, part, (long)4 * 16384, mu, ld2, rank_g, out);
  }
}